// Round 4
// baseline (901.683 us; speedup 1.0000x reference)
//
#include <hip/hip_runtime.h>
#include <math.h>

#define DM 1024
#define DF 4096
#define NE 24
#define T_TOK 4096
#define T2 (T_TOK*2)

#define BM 128
#define BN 128
#define BK 64
#define LDK 72          // padded LDS row stride in shorts (144 B)
#define MTILES 8        // max 1024 tokens per expert (measured ~341 +/- 20)
#define NK1 (DM / BK)   // 16
#define NK2 (DF / BK)   // 64

typedef __attribute__((ext_vector_type(4))) float f32x4;
typedef __attribute__((ext_vector_type(8))) short s16x8;

// exact RNE fp32 -> bf16 (finite inputs)
static __device__ __forceinline__ unsigned short f2bf(float f) {
    unsigned int u = __float_as_uint(f);
    unsigned int r = u + 0x7fffu + ((u >> 16) & 1u);
    return (unsigned short)(r >> 16);
}

// ---------------- gating ----------------

__global__ void k_transpose_gw(const float* __restrict__ gw, float* __restrict__ gwT) {
    int e = blockIdx.x;
    for (int d = threadIdx.x; d < DM; d += blockDim.x)
        gwT[e * DM + d] = gw[d * NE + e];
}

__global__ void k_gate(const float* __restrict__ x, const float* __restrict__ gwT,
                       const float* __restrict__ gb,
                       int* __restrict__ idx, float* __restrict__ prob) {
    int wave = threadIdx.x >> 6;
    int lane = threadIdx.x & 63;
    int t = blockIdx.x * 4 + wave;
    if (t >= T_TOK) return;
    const float* xr = x + (size_t)t * DM;
    float acc[NE];
#pragma unroll
    for (int e = 0; e < NE; e++) acc[e] = 0.f;
    for (int i = 0; i < DM / 64; i++) {
        int d = lane + i * 64;
        float xv = xr[d];
#pragma unroll
        for (int e = 0; e < NE; e++) acc[e] = fmaf(xv, gwT[e * DM + d], acc[e]);
    }
#pragma unroll
    for (int e = 0; e < NE; e++) {
        float v = acc[e];
        for (int off = 32; off >= 1; off >>= 1) v += __shfl_xor(v, off);
        acc[e] = v;
    }
    if (lane == 0) {
        float v1 = -1e30f, v2 = -1e30f;
        int i1 = -1, i2 = -1;
        for (int e = 0; e < NE; e++) {
            float s = acc[e] + gb[e];
            if (s > v1) { v2 = v1; i2 = i1; v1 = s; i1 = e; }
            else if (s > v2) { v2 = s; i2 = e; }
        }
        float e2 = expf(v2 - v1);
        float inv = 1.f / (1.f + e2);
        idx[t * 2] = i1; idx[t * 2 + 1] = i2;
        prob[t * 2] = inv; prob[t * 2 + 1] = e2 * inv;
    }
}

// ---------------- routing ----------------

__global__ void k_zero(int* counts, int* cursors) {
    int i = threadIdx.x;
    if (i < NE) { counts[i] = 0; cursors[i] = 0; }
}

__global__ void k_count(const int* __restrict__ idx, int* counts) {
    int i = blockIdx.x * blockDim.x + threadIdx.x;
    if (i < T2) atomicAdd(&counts[idx[i]], 1);
}

__global__ void k_scan(const int* __restrict__ counts, int* offsets) {
    if (threadIdx.x == 0) {
        int s = 0;
        for (int e = 0; e < NE; e++) { offsets[e] = s; s += counts[e]; }
        offsets[NE] = s;
    }
}

// also writes the inverse map pair -> slot position
__global__ void k_scatter(const int* __restrict__ idx,
                          const int* __restrict__ offsets, int* cursors,
                          int* __restrict__ slot_tok, int* __restrict__ pair_slot) {
    int i = blockIdx.x * blockDim.x + threadIdx.x;
    if (i < T2) {
        int e = idx[i];
        int pos = offsets[e] + atomicAdd(&cursors[e], 1);
        slot_tok[pos] = i >> 1;
        pair_slot[i] = pos;
    }
}

// gather routed token rows into dense bf16 slot-major matrix Xg[slot][DM]
__global__ void k_gather(const float* __restrict__ x, const int* __restrict__ slot_tok,
                         unsigned short* __restrict__ Xg) {
    int s = blockIdx.x;
    int tok = slot_tok[s];
    const float4* src = (const float4*)(x + (size_t)tok * DM);
    ushort4* dst = (ushort4*)(Xg + (size_t)s * DM);
    for (int i = threadIdx.x; i < DM / 4; i += blockDim.x) {
        float4 v = src[i];
        ushort4 o;
        o.x = f2bf(v.x); o.y = f2bf(v.y); o.z = f2bf(v.z); o.w = f2bf(v.w);
        dst[i] = o;
    }
}

// out[t] = p1*(Y[s1]+b2[e1]) + p2*(Y[s2]+b2[e2])
__global__ void k_combine(const float* __restrict__ Y, const int* __restrict__ pair_slot,
                          const float* __restrict__ prob, const int* __restrict__ idx,
                          const float* __restrict__ b2, float* __restrict__ out) {
    int t = blockIdx.x;
    int s1 = pair_slot[t * 2], s2 = pair_slot[t * 2 + 1];
    int e1 = idx[t * 2], e2 = idx[t * 2 + 1];
    float p1 = prob[t * 2], p2 = prob[t * 2 + 1];
    const float4* y1 = (const float4*)(Y + (size_t)s1 * DM);
    const float4* y2 = (const float4*)(Y + (size_t)s2 * DM);
    const float4* ba = (const float4*)(b2 + (size_t)e1 * DM);
    const float4* bb = (const float4*)(b2 + (size_t)e2 * DM);
    float4* o = (float4*)(out + (size_t)t * DM);
    int i = threadIdx.x;   // 256 threads x float4 == 1024
    float4 a = y1[i], b = y2[i], c = ba[i], d = bb[i];
    float4 r;
    r.x = p1 * (a.x + c.x) + p2 * (b.x + d.x);
    r.y = p1 * (a.y + c.y) + p2 * (b.y + d.y);
    r.z = p1 * (a.z + c.z) + p2 * (b.z + d.z);
    r.w = p1 * (a.w + c.w) + p2 * (b.w + d.w);
    o[i] = r;
}

// ---------------- FFN1: H = gelu(Xg @ W1e + b1)  [bf16 MFMA, 2-phase] ----------------
// grid: (DF/BN, NE*MTILES); 256 threads = 4 waves (2x2), tile 128x128, BK=64
// __launch_bounds__(256,2): VGPR cap 256 — acc(64)+areg(16)+breg(32)+addr must
// stay in registers; round-3's default cap (VGPR=84) spilled the staging regs.

__global__ __launch_bounds__(256, 2)
void k_ffn1(const unsigned short* __restrict__ Xg, const float* __restrict__ w1,
            const float* __restrict__ b1, const int* __restrict__ counts,
            const int* __restrict__ offsets, unsigned short* __restrict__ H) {
    const int emt = blockIdx.y;
    const int e = emt / MTILES, mt = emt % MTILES;
    const int ne = counts[e];
    const int m0 = mt * BM;
    if (m0 >= ne) return;
    const int rows = min(BM, ne - m0);
    const int n0 = blockIdx.x * BN;
    const int slotbase = offsets[e] + m0;

    __shared__ unsigned short As[BM * LDK];
    __shared__ unsigned short Bs[BN * LDK];

    const int tid  = threadIdx.x;
    const int lane = tid & 63;
    const int wid  = tid >> 6;
    const int wm   = wid >> 1, wn = wid & 1;

    const float* w1e = w1 + (size_t)e * DM * DF;

    f32x4 acc[4][4];
#pragma unroll
    for (int a = 0; a < 4; a++)
#pragma unroll
        for (int b = 0; b < 4; b++) acc[a][b] = (f32x4)0.f;

    const int am = tid >> 1;
    const int ac = (tid & 1) * 4;
    const unsigned short* asrc = Xg + (size_t)(slotbase + am) * DM + ac * 8;
    unsigned short* adst = &As[am * LDK + ac * 8];

    const int bn  = tid & 127;
    const int bkh = (tid >> 7) * 32;
    unsigned short* bdst = &Bs[bn * LDK + bkh];

    int4  areg[4];
    float breg[4][8];

    auto loadAB = [&](int k0) {
#pragma unroll
        for (int j = 0; j < 4; j++)
            areg[j] = *(const int4*)(asrc + k0 + j * 8);
#pragma unroll
        for (int j = 0; j < 4; j++)
#pragma unroll
            for (int i = 0; i < 8; i++)
                breg[j][i] = w1e[(size_t)(k0 + bkh + j * 8 + i) * DF + n0 + bn];
    };

    loadAB(0);
#pragma unroll 1
    for (int kt = 0; kt < NK1; ++kt) {
        __syncthreads();
#pragma unroll
        for (int j = 0; j < 4; j++)
            *(int4*)(adst + j * 8) = areg[j];
#pragma unroll
        for (int j = 0; j < 4; j++) {
            s16x8 bp;
#pragma unroll
            for (int i = 0; i < 8; i++) bp[i] = (short)f2bf(breg[j][i]);
            *(s16x8*)(bdst + j * 8) = bp;
        }
        __syncthreads();
        if (kt + 1 < NK1) loadAB((kt + 1) * BK);   // in flight across the MFMA phase
#pragma unroll
        for (int ks = 0; ks < 2; ks++) {
            const int ko = ks * 32 + (lane >> 4) * 8;
            s16x8 af[4], bfr[4];
#pragma unroll
            for (int f = 0; f < 4; f++)
                af[f] = *(const s16x8*)&As[(wm * 64 + f * 16 + (lane & 15)) * LDK + ko];
#pragma unroll
            for (int f = 0; f < 4; f++)
                bfr[f] = *(const s16x8*)&Bs[(wn * 64 + f * 16 + (lane & 15)) * LDK + ko];
#pragma unroll
            for (int fm = 0; fm < 4; fm++)
#pragma unroll
                for (int fn = 0; fn < 4; fn++)
                    acc[fm][fn] = __builtin_amdgcn_mfma_f32_16x16x32_bf16(
                        af[fm], bfr[fn], acc[fm][fn], 0, 0, 0);
        }
    }

    const float* b1e = b1 + (size_t)e * DF;
#pragma unroll
    for (int fm = 0; fm < 4; fm++) {
        const int mrow = wm * 64 + fm * 16 + ((lane >> 4) << 2);
#pragma unroll
        for (int fn = 0; fn < 4; fn++) {
            const int ncol = n0 + wn * 64 + fn * 16 + (lane & 15);
            const float bb = b1e[ncol];
#pragma unroll
            for (int r = 0; r < 4; r++) {
                const int m = mrow + r;
                if (m < rows) {
                    float h = acc[fm][fn][r] + bb;
                    h = 0.5f * h * (1.f + erff(h * 0.70710678118654752f));
                    H[(size_t)(slotbase + m) * DF + ncol] = f2bf(h);
                }
            }
        }
    }
}

// ---------------- FFN2: Y = H @ W2e  [bf16 MFMA, 2-phase, plain stores] ----------------
// grid: (DM/BN, NE*MTILES)

__global__ __launch_bounds__(256, 2)
void k_ffn2(const unsigned short* __restrict__ H, const float* __restrict__ w2,
            const int* __restrict__ counts, const int* __restrict__ offsets,
            float* __restrict__ Y) {
    const int emt = blockIdx.y;
    const int e = emt / MTILES, mt = emt % MTILES;
    const int ne = counts[e];
    const int m0 = mt * BM;
    if (m0 >= ne) return;
    const int rows = min(BM, ne - m0);
    const int n0 = blockIdx.x * BN;
    const int slotbase = offsets[e] + m0;

    __shared__ unsigned short As[BM * LDK];
    __shared__ unsigned short Bs[BN * LDK];

    const int tid  = threadIdx.x;
    const int lane = tid & 63;
    const int wid  = tid >> 6;
    const int wm   = wid >> 1, wn = wid & 1;

    const float* w2e = w2 + (size_t)e * DF * DM;

    f32x4 acc[4][4];
#pragma unroll
    for (int a = 0; a < 4; a++)
#pragma unroll
        for (int b = 0; b < 4; b++) acc[a][b] = (f32x4)0.f;

    const int am = tid >> 1;
    const int ac = (tid & 1) * 4;
    const unsigned short* asrc = H + (size_t)(slotbase + am) * DF + ac * 8;
    unsigned short* adst = &As[am * LDK + ac * 8];

    const int bn  = tid & 127;
    const int bkh = (tid >> 7) * 32;
    unsigned short* bdst = &Bs[bn * LDK + bkh];

    int4  areg[4];
    float breg[4][8];

    auto loadAB = [&](int k0) {
#pragma unroll
        for (int j = 0; j < 4; j++)
            areg[j] = *(const int4*)(asrc + k0 + j * 8);
#pragma unroll
        for (int j = 0; j < 4; j++)
#pragma unroll
            for (int i = 0; i < 8; i++)
                breg[j][i] = w2e[(size_t)(k0 + bkh + j * 8 + i) * DM + n0 + bn];
    };

    loadAB(0);
#pragma unroll 1
    for (int kt = 0; kt < NK2; ++kt) {
        __syncthreads();
#pragma unroll
        for (int j = 0; j < 4; j++)
            *(int4*)(adst + j * 8) = areg[j];
#pragma unroll
        for (int j = 0; j < 4; j++) {
            s16x8 bp;
#pragma unroll
            for (int i = 0; i < 8; i++) bp[i] = (short)f2bf(breg[j][i]);
            *(s16x8*)(bdst + j * 8) = bp;
        }
        __syncthreads();
        if (kt + 1 < NK2) loadAB((kt + 1) * BK);
#pragma unroll
        for (int ks = 0; ks < 2; ks++) {
            const int ko = ks * 32 + (lane >> 4) * 8;
            s16x8 af[4], bfr[4];
#pragma unroll
            for (int f = 0; f < 4; f++)
                af[f] = *(const s16x8*)&As[(wm * 64 + f * 16 + (lane & 15)) * LDK + ko];
#pragma unroll
            for (int f = 0; f < 4; f++)
                bfr[f] = *(const s16x8*)&Bs[(wn * 64 + f * 16 + (lane & 15)) * LDK + ko];
#pragma unroll
            for (int fm = 0; fm < 4; fm++)
#pragma unroll
                for (int fn = 0; fn < 4; fn++)
                    acc[fm][fn] = __builtin_amdgcn_mfma_f32_16x16x32_bf16(
                        af[fm], bfr[fn], acc[fm][fn], 0, 0, 0);
        }
    }

#pragma unroll
    for (int fm = 0; fm < 4; fm++) {
        const int mrow = wm * 64 + fm * 16 + ((lane >> 4) << 2);
#pragma unroll
        for (int fn = 0; fn < 4; fn++) {
            const int ncol = n0 + wn * 64 + fn * 16 + (lane & 15);
#pragma unroll
            for (int r = 0; r < 4; r++) {
                const int m = mrow + r;
                if (m < rows)
                    Y[(size_t)(slotbase + m) * DM + ncol] = acc[fm][fn][r];
            }
        }
    }
}

// ---------------- launch ----------------

extern "C" void kernel_launch(void* const* d_in, const int* in_sizes, int n_in,
                              void* d_out, int out_size, void* d_ws, size_t ws_size,
                              hipStream_t stream) {
    const float* x   = (const float*)d_in[0];
    const float* gw  = (const float*)d_in[1];
    const float* gb  = (const float*)d_in[2];
    const float* w1  = (const float*)d_in[3];
    const float* b1  = (const float*)d_in[4];
    const float* w2  = (const float*)d_in[5];
    const float* b2  = (const float*)d_in[6];
    float* out = (float*)d_out;

    size_t off = 0;
    auto alloc = [&](size_t bytes) {
        void* p = (char*)d_ws + off;
        off += (bytes + 255) & ~(size_t)255;
        return p;
    };
    float* gwT       = (float*)alloc(NE * DM * sizeof(float));
    int*   idx       = (int*)alloc(T2 * sizeof(int));
    float* prob      = (float*)alloc(T2 * sizeof(float));
    int*   counts    = (int*)alloc(32 * sizeof(int));
    int*   offsets   = (int*)alloc(32 * sizeof(int));
    int*   cursors   = (int*)alloc(32 * sizeof(int));
    int*   slot_tok  = (int*)alloc(T2 * sizeof(int));
    int*   pair_slot = (int*)alloc(T2 * sizeof(int));
    unsigned short* Xg = (unsigned short*)alloc((size_t)(T2 + BM) * DM * sizeof(unsigned short));
    unsigned short* Hb = (unsigned short*)alloc((size_t)(T2 + BM) * DF * sizeof(unsigned short));
    float* Yb        = (float*)alloc((size_t)(T2 + BM) * DM * sizeof(float));

    k_transpose_gw<<<NE, 256, 0, stream>>>(gw, gwT);
    k_gate<<<T_TOK / 4, 256, 0, stream>>>(x, gwT, gb, idx, prob);
    k_zero<<<1, 64, 0, stream>>>(counts, cursors);
    k_count<<<T2 / 256, 256, 0, stream>>>(idx, counts);
    k_scan<<<1, 64, 0, stream>>>(counts, offsets);
    k_scatter<<<T2 / 256, 256, 0, stream>>>(idx, offsets, cursors, slot_tok, pair_slot);
    k_gather<<<T2, 256, 0, stream>>>(x, slot_tok, Xg);

    dim3 g1(DF / BN, NE * MTILES);
    k_ffn1<<<g1, 256, 0, stream>>>(Xg, w1, b1, counts, offsets, Hb);
    dim3 g2(DM / BN, NE * MTILES);
    k_ffn2<<<g2, 256, 0, stream>>>(Hb, w2, counts, offsets, Yb);
    k_combine<<<T_TOK, 256, 0, stream>>>(Yb, pair_slot, prob, idx, b2, out);
}

// Round 5
// 739.596 us; speedup vs baseline: 1.2192x; 1.2192x over previous
//
#include <hip/hip_runtime.h>
#include <math.h>

#define DM 1024
#define DF 4096
#define NE 24
#define T_TOK 4096
#define T2 (T_TOK*2)

#define BM 128
#define BN 128
#define BK 64
#define LDK 72          // padded LDS stride for fallback kernels
#define MTILES 8
#define NK1 (DM / BK)   // 16
#define NK2 (DF / BK)   // 64

typedef __attribute__((ext_vector_type(4))) float f32x4;
typedef __attribute__((ext_vector_type(8))) short s16x8;

// exact RNE fp32 -> bf16 (finite inputs)
static __device__ __forceinline__ unsigned short f2bf(float f) {
    unsigned int u = __float_as_uint(f);
    unsigned int r = u + 0x7fffu + ((u >> 16) & 1u);
    return (unsigned short)(r >> 16);
}

// async global->LDS, 16B per lane; lds dest is wave-uniform base + lane*16
#define GLL(gsrc, ldst)                                                          \
    __builtin_amdgcn_global_load_lds(                                            \
        (const __attribute__((address_space(1))) void*)(gsrc),                   \
        (__attribute__((address_space(3))) void*)(ldst), 16, 0, 0)

// ---------------- gating ----------------

__global__ void k_transpose_gw(const float* __restrict__ gw, float* __restrict__ gwT) {
    int e = blockIdx.x;
    for (int d = threadIdx.x; d < DM; d += blockDim.x)
        gwT[e * DM + d] = gw[d * NE + e];
}

__global__ void k_gate(const float* __restrict__ x, const float* __restrict__ gwT,
                       const float* __restrict__ gb,
                       int* __restrict__ idx, float* __restrict__ prob) {
    int wave = threadIdx.x >> 6;
    int lane = threadIdx.x & 63;
    int t = blockIdx.x * 4 + wave;
    if (t >= T_TOK) return;
    const float* xr = x + (size_t)t * DM;
    float acc[NE];
#pragma unroll
    for (int e = 0; e < NE; e++) acc[e] = 0.f;
    for (int i = 0; i < DM / 64; i++) {
        int d = lane + i * 64;
        float xv = xr[d];
#pragma unroll
        for (int e = 0; e < NE; e++) acc[e] = fmaf(xv, gwT[e * DM + d], acc[e]);
    }
#pragma unroll
    for (int e = 0; e < NE; e++) {
        float v = acc[e];
        for (int off = 32; off >= 1; off >>= 1) v += __shfl_xor(v, off);
        acc[e] = v;
    }
    if (lane == 0) {
        float v1 = -1e30f, v2 = -1e30f;
        int i1 = -1, i2 = -1;
        for (int e = 0; e < NE; e++) {
            float s = acc[e] + gb[e];
            if (s > v1) { v2 = v1; i2 = i1; v1 = s; i1 = e; }
            else if (s > v2) { v2 = s; i2 = e; }
        }
        float e2 = expf(v2 - v1);
        float inv = 1.f / (1.f + e2);
        idx[t * 2] = i1; idx[t * 2 + 1] = i2;
        prob[t * 2] = inv; prob[t * 2 + 1] = e2 * inv;
    }
}

// ---------------- routing ----------------

__global__ void k_zero(int* counts, int* cursors) {
    int i = threadIdx.x;
    if (i < NE) { counts[i] = 0; cursors[i] = 0; }
}

__global__ void k_count(const int* __restrict__ idx, int* counts) {
    int i = blockIdx.x * blockDim.x + threadIdx.x;
    if (i < T2) atomicAdd(&counts[idx[i]], 1);
}

__global__ void k_scan(const int* __restrict__ counts, int* offsets) {
    if (threadIdx.x == 0) {
        int s = 0;
        for (int e = 0; e < NE; e++) { offsets[e] = s; s += counts[e]; }
        offsets[NE] = s;
    }
}

__global__ void k_scatter(const int* __restrict__ idx,
                          const int* __restrict__ offsets, int* cursors,
                          int* __restrict__ slot_tok, int* __restrict__ pair_slot) {
    int i = blockIdx.x * blockDim.x + threadIdx.x;
    if (i < T2) {
        int e = idx[i];
        int pos = offsets[e] + atomicAdd(&cursors[e], 1);
        slot_tok[pos] = i >> 1;
        pair_slot[i] = pos;
    }
}

__global__ void k_gather(const float* __restrict__ x, const int* __restrict__ slot_tok,
                         unsigned short* __restrict__ Xg) {
    int s = blockIdx.x;
    int tok = slot_tok[s];
    const float4* src = (const float4*)(x + (size_t)tok * DM);
    ushort4* dst = (ushort4*)(Xg + (size_t)s * DM);
    for (int i = threadIdx.x; i < DM / 4; i += blockDim.x) {
        float4 v = src[i];
        ushort4 o;
        o.x = f2bf(v.x); o.y = f2bf(v.y); o.z = f2bf(v.z); o.w = f2bf(v.w);
        dst[i] = o;
    }
}

__global__ void k_combine(const float* __restrict__ Y, const int* __restrict__ pair_slot,
                          const float* __restrict__ prob, const int* __restrict__ idx,
                          const float* __restrict__ b2, float* __restrict__ out) {
    int t = blockIdx.x;
    int s1 = pair_slot[t * 2], s2 = pair_slot[t * 2 + 1];
    int e1 = idx[t * 2], e2 = idx[t * 2 + 1];
    float p1 = prob[t * 2], p2 = prob[t * 2 + 1];
    const float4* y1 = (const float4*)(Y + (size_t)s1 * DM);
    const float4* y2 = (const float4*)(Y + (size_t)s2 * DM);
    const float4* ba = (const float4*)(b2 + (size_t)e1 * DM);
    const float4* bb = (const float4*)(b2 + (size_t)e2 * DM);
    float4* o = (float4*)(out + (size_t)t * DM);
    int i = threadIdx.x;
    float4 a = y1[i], b = y2[i], c = ba[i], d = bb[i];
    float4 r;
    r.x = p1 * (a.x + c.x) + p2 * (b.x + d.x);
    r.y = p1 * (a.y + c.y) + p2 * (b.y + d.y);
    r.z = p1 * (a.z + c.z) + p2 * (b.z + d.z);
    r.w = p1 * (a.w + c.w) + p2 * (b.w + d.w);
    o[i] = r;
}

// ---------------- transpose+convert: W[K][N] fp32 -> WT[N][K] bf16 ----------------
// grid: (N/64, K/64, NE), 256 threads, 64x64 tiles via LDS

__global__ __launch_bounds__(256)
void k_convT(const float* __restrict__ W, unsigned short* __restrict__ WT,
             int K, int N) {
    const int e = blockIdx.z;
    const int n0 = blockIdx.x * 64, k0 = blockIdx.y * 64;
    const float* we = W + (size_t)e * K * N;
    unsigned short* wte = WT + (size_t)e * K * N;
    __shared__ float T[64][65];
    const int t = threadIdx.x;
    const int rr = t >> 4, cc = (t & 15) * 4;
#pragma unroll
    for (int p = 0; p < 4; p++) {
        const float* src = we + (size_t)(k0 + rr + p * 16) * N + n0 + cc;
        float4 v = *(const float4*)src;
        T[rr + p * 16][cc + 0] = v.x;
        T[rr + p * 16][cc + 1] = v.y;
        T[rr + p * 16][cc + 2] = v.z;
        T[rr + p * 16][cc + 3] = v.w;
    }
    __syncthreads();
    const int n = t >> 2;
#pragma unroll
    for (int p = 0; p < 4; p++) {
        int kq = ((t & 3) + p * 4) * 4;
        ushort4 o;
        o.x = f2bf(T[kq + 0][n]);
        o.y = f2bf(T[kq + 1][n]);
        o.z = f2bf(T[kq + 2][n]);
        o.w = f2bf(T[kq + 3][n]);
        *(ushort4*)(wte + (size_t)(n0 + n) * K + k0 + kq) = o;
    }
}

// ---------------- MM1: H = gelu(Xg @ W1T^T + b1)  [global_load_lds, dbuf] ----------------
// A = Xg [slot][DM] bf16; BT = W1T [n(DF)][k(DM)] bf16; grid (DF/BN, NE*MTILES)

__global__ __launch_bounds__(256)
void k_mm1(const unsigned short* __restrict__ Xg, const unsigned short* __restrict__ W1T,
           const float* __restrict__ b1, const int* __restrict__ counts,
           const int* __restrict__ offsets, unsigned short* __restrict__ H) {
    const int emt = blockIdx.y;
    const int e = emt / MTILES, mt = emt % MTILES;
    const int ne = counts[e];
    const int m0 = mt * BM;
    if (m0 >= ne) return;
    const int rows = min(BM, ne - m0);
    const int n0 = blockIdx.x * BN;
    const int slotbase = offsets[e] + m0;

    __shared__ unsigned short As[2][BM * BK];   // linear [row][k], 128B rows
    __shared__ unsigned short Bs[2][BN * BK];

    const int tid  = threadIdx.x;
    const int lane = tid & 63;
    const int w    = tid >> 6;
    const int wm   = w >> 1, wn = w & 1;

    const unsigned short* bte = W1T + (size_t)e * (size_t)DF * DM;
    const int arow = (lane >> 3);       // 0..7 within 8-row group
    const int kofs = (lane & 7) * 8;    // element offset within row

    f32x4 acc[4][4];
#pragma unroll
    for (int a = 0; a < 4; a++)
#pragma unroll
        for (int b = 0; b < 4; b++) acc[a][b] = (f32x4)0.f;

    auto stage = [&](int buf, int k0) {
#pragma unroll
        for (int q = 0; q < 4; q++) {
            int row = (w * 4 + q) * 8 + arow;
            GLL(Xg + (size_t)(slotbase + row) * DM + k0 + kofs,
                &As[buf][(w * 4 + q) * 512]);
            GLL(bte + (size_t)(n0 + row) * DM + k0 + kofs,
                &Bs[buf][(w * 4 + q) * 512]);
        }
    };

    stage(0, 0);
    __syncthreads();
    int cur = 0;
#pragma unroll 1
    for (int kt = 0; kt < NK1; ++kt) {
        if (kt + 1 < NK1) stage(cur ^ 1, (kt + 1) * BK);
#pragma unroll
        for (int ks = 0; ks < 2; ks++) {
            const int ko = ks * 32 + (lane >> 4) * 8;
            s16x8 af[4], bfr[4];
#pragma unroll
            for (int f = 0; f < 4; f++)
                af[f] = *(const s16x8*)&As[cur][(wm * 64 + f * 16 + (lane & 15)) * BK + ko];
#pragma unroll
            for (int f = 0; f < 4; f++)
                bfr[f] = *(const s16x8*)&Bs[cur][(wn * 64 + f * 16 + (lane & 15)) * BK + ko];
#pragma unroll
            for (int fm = 0; fm < 4; fm++)
#pragma unroll
                for (int fn = 0; fn < 4; fn++)
                    acc[fm][fn] = __builtin_amdgcn_mfma_f32_16x16x32_bf16(
                        af[fm], bfr[fn], acc[fm][fn], 0, 0, 0);
        }
        __syncthreads();
        cur ^= 1;
    }

    const float* b1e = b1 + (size_t)e * DF;
#pragma unroll
    for (int fm = 0; fm < 4; fm++) {
        const int mrow = wm * 64 + fm * 16 + ((lane >> 4) << 2);
#pragma unroll
        for (int fn = 0; fn < 4; fn++) {
            const int ncol = n0 + wn * 64 + fn * 16 + (lane & 15);
            const float bb = b1e[ncol];
#pragma unroll
            for (int r = 0; r < 4; r++) {
                const int m = mrow + r;
                if (m < rows) {
                    float h = acc[fm][fn][r] + bb;
                    h = 0.5f * h * (1.f + erff(h * 0.70710678118654752f));
                    H[(size_t)(slotbase + m) * DF + ncol] = f2bf(h);
                }
            }
        }
    }
}

// ---------------- MM2: Y = H @ W2T^T  [global_load_lds, dbuf] ----------------
// A = Hb [slot][DF] bf16; BT = W2T [n(DM)][k(DF)] bf16; grid (DM/BN, NE*MTILES)

__global__ __launch_bounds__(256)
void k_mm2(const unsigned short* __restrict__ Hb, const unsigned short* __restrict__ W2T,
           const int* __restrict__ counts, const int* __restrict__ offsets,
           float* __restrict__ Y) {
    const int emt = blockIdx.y;
    const int e = emt / MTILES, mt = emt % MTILES;
    const int ne = counts[e];
    const int m0 = mt * BM;
    if (m0 >= ne) return;
    const int rows = min(BM, ne - m0);
    const int n0 = blockIdx.x * BN;
    const int slotbase = offsets[e] + m0;

    __shared__ unsigned short As[2][BM * BK];
    __shared__ unsigned short Bs[2][BN * BK];

    const int tid  = threadIdx.x;
    const int lane = tid & 63;
    const int w    = tid >> 6;
    const int wm   = w >> 1, wn = w & 1;

    const unsigned short* bte = W2T + (size_t)e * (size_t)DF * DM;
    const int arow = (lane >> 3);
    const int kofs = (lane & 7) * 8;

    f32x4 acc[4][4];
#pragma unroll
    for (int a = 0; a < 4; a++)
#pragma unroll
        for (int b = 0; b < 4; b++) acc[a][b] = (f32x4)0.f;

    auto stage = [&](int buf, int k0) {
#pragma unroll
        for (int q = 0; q < 4; q++) {
            int row = (w * 4 + q) * 8 + arow;
            GLL(Hb + (size_t)(slotbase + row) * DF + k0 + kofs,
                &As[buf][(w * 4 + q) * 512]);
            GLL(bte + (size_t)(n0 + row) * DF + k0 + kofs,
                &Bs[buf][(w * 4 + q) * 512]);
        }
    };

    stage(0, 0);
    __syncthreads();
    int cur = 0;
#pragma unroll 1
    for (int kt = 0; kt < NK2; ++kt) {
        if (kt + 1 < NK2) stage(cur ^ 1, (kt + 1) * BK);
#pragma unroll
        for (int ks = 0; ks < 2; ks++) {
            const int ko = ks * 32 + (lane >> 4) * 8;
            s16x8 af[4], bfr[4];
#pragma unroll
            for (int f = 0; f < 4; f++)
                af[f] = *(const s16x8*)&As[cur][(wm * 64 + f * 16 + (lane & 15)) * BK + ko];
#pragma unroll
            for (int f = 0; f < 4; f++)
                bfr[f] = *(const s16x8*)&Bs[cur][(wn * 64 + f * 16 + (lane & 15)) * BK + ko];
#pragma unroll
            for (int fm = 0; fm < 4; fm++)
#pragma unroll
                for (int fn = 0; fn < 4; fn++)
                    acc[fm][fn] = __builtin_amdgcn_mfma_f32_16x16x32_bf16(
                        af[fm], bfr[fn], acc[fm][fn], 0, 0, 0);
        }
        __syncthreads();
        cur ^= 1;
    }

#pragma unroll
    for (int fm = 0; fm < 4; fm++) {
        const int mrow = wm * 64 + fm * 16 + ((lane >> 4) << 2);
#pragma unroll
        for (int fn = 0; fn < 4; fn++) {
            const int ncol = n0 + wn * 64 + fn * 16 + (lane & 15);
#pragma unroll
            for (int r = 0; r < 4; r++) {
                const int m = mrow + r;
                if (m < rows)
                    Y[(size_t)(slotbase + m) * DM + ncol] = acc[fm][fn][r];
            }
        }
    }
}

// ---------------- fallback FFN kernels (R3 path, reg-staged) ----------------

__global__ __launch_bounds__(256)
void k_ffn1_o(const unsigned short* __restrict__ Xg, const float* __restrict__ w1,
              const float* __restrict__ b1, const int* __restrict__ counts,
              const int* __restrict__ offsets, unsigned short* __restrict__ H) {
    const int emt = blockIdx.y;
    const int e = emt / MTILES, mt = emt % MTILES;
    const int ne = counts[e];
    const int m0 = mt * BM;
    if (m0 >= ne) return;
    const int rows = min(BM, ne - m0);
    const int n0 = blockIdx.x * BN;
    const int slotbase = offsets[e] + m0;

    __shared__ unsigned short As[BM * LDK];
    __shared__ unsigned short Bs[BN * LDK];

    const int tid  = threadIdx.x;
    const int lane = tid & 63;
    const int wid  = tid >> 6;
    const int wm   = wid >> 1, wn = wid & 1;

    const float* w1e = w1 + (size_t)e * DM * DF;

    f32x4 acc[4][4];
#pragma unroll
    for (int a = 0; a < 4; a++)
#pragma unroll
        for (int b = 0; b < 4; b++) acc[a][b] = (f32x4)0.f;

    const int am = tid >> 1;
    const int ac = (tid & 1) * 4;
    const unsigned short* asrc = Xg + (size_t)(slotbase + am) * DM + ac * 8;
    unsigned short* adst = &As[am * LDK + ac * 8];
    const int bn  = tid & 127;
    const int bkh = (tid >> 7) * 32;
    unsigned short* bdst = &Bs[bn * LDK + bkh];

    for (int k0 = 0; k0 < DM; k0 += BK) {
        int4 av[4];
#pragma unroll
        for (int j = 0; j < 4; j++) av[j] = *(const int4*)(asrc + k0 + j * 8);
        s16x8 bp[4];
#pragma unroll
        for (int j = 0; j < 4; j++) {
            float t[8];
#pragma unroll
            for (int i = 0; i < 8; i++)
                t[i] = w1e[(size_t)(k0 + bkh + j * 8 + i) * DF + n0 + bn];
#pragma unroll
            for (int i = 0; i < 8; i++) bp[j][i] = (short)f2bf(t[i]);
        }
        __syncthreads();
#pragma unroll
        for (int j = 0; j < 4; j++) *(int4*)(adst + j * 8) = av[j];
#pragma unroll
        for (int j = 0; j < 4; j++) *(s16x8*)(bdst + j * 8) = bp[j];
        __syncthreads();
#pragma unroll
        for (int ks = 0; ks < 2; ks++) {
            const int ko = ks * 32 + (lane >> 4) * 8;
            s16x8 af[4], bfr[4];
#pragma unroll
            for (int f = 0; f < 4; f++)
                af[f] = *(const s16x8*)&As[(wm * 64 + f * 16 + (lane & 15)) * LDK + ko];
#pragma unroll
            for (int f = 0; f < 4; f++)
                bfr[f] = *(const s16x8*)&Bs[(wn * 64 + f * 16 + (lane & 15)) * LDK + ko];
#pragma unroll
            for (int fm = 0; fm < 4; fm++)
#pragma unroll
                for (int fn = 0; fn < 4; fn++)
                    acc[fm][fn] = __builtin_amdgcn_mfma_f32_16x16x32_bf16(
                        af[fm], bfr[fn], acc[fm][fn], 0, 0, 0);
        }
    }

    const float* b1e = b1 + (size_t)e * DF;
#pragma unroll
    for (int fm = 0; fm < 4; fm++) {
        const int mrow = wm * 64 + fm * 16 + ((lane >> 4) << 2);
#pragma unroll
        for (int fn = 0; fn < 4; fn++) {
            const int ncol = n0 + wn * 64 + fn * 16 + (lane & 15);
            const float bb = b1e[ncol];
#pragma unroll
            for (int r = 0; r < 4; r++) {
                const int m = mrow + r;
                if (m < rows) {
                    float h = acc[fm][fn][r] + bb;
                    h = 0.5f * h * (1.f + erff(h * 0.70710678118654752f));
                    H[(size_t)(slotbase + m) * DF + ncol] = f2bf(h);
                }
            }
        }
    }
}

__global__ __launch_bounds__(256)
void k_ffn2_o(const unsigned short* __restrict__ H, const float* __restrict__ w2,
              const int* __restrict__ counts, const int* __restrict__ offsets,
              float* __restrict__ Y) {
    const int emt = blockIdx.y;
    const int e = emt / MTILES, mt = emt % MTILES;
    const int ne = counts[e];
    const int m0 = mt * BM;
    if (m0 >= ne) return;
    const int rows = min(BM, ne - m0);
    const int n0 = blockIdx.x * BN;
    const int slotbase = offsets[e] + m0;

    __shared__ unsigned short As[BM * LDK];
    __shared__ unsigned short Bs[BN * LDK];

    const int tid  = threadIdx.x;
    const int lane = tid & 63;
    const int wid  = tid >> 6;
    const int wm   = wid >> 1, wn = wid & 1;

    const float* w2e = w2 + (size_t)e * DF * DM;

    f32x4 acc[4][4];
#pragma unroll
    for (int a = 0; a < 4; a++)
#pragma unroll
        for (int b = 0; b < 4; b++) acc[a][b] = (f32x4)0.f;

    const int am = tid >> 1;
    const int ac = (tid & 1) * 4;
    const unsigned short* asrc = H + (size_t)(slotbase + am) * DF + ac * 8;
    unsigned short* adst = &As[am * LDK + ac * 8];
    const int bn  = tid & 127;
    const int bkh = (tid >> 7) * 32;
    unsigned short* bdst = &Bs[bn * LDK + bkh];

    for (int k0 = 0; k0 < DF; k0 += BK) {
        int4 av[4];
#pragma unroll
        for (int j = 0; j < 4; j++) av[j] = *(const int4*)(asrc + k0 + j * 8);
        s16x8 bp[4];
#pragma unroll
        for (int j = 0; j < 4; j++) {
            float t[8];
#pragma unroll
            for (int i = 0; i < 8; i++)
                t[i] = w2e[(size_t)(k0 + bkh + j * 8 + i) * DM + n0 + bn];
#pragma unroll
            for (int i = 0; i < 8; i++) bp[j][i] = (short)f2bf(t[i]);
        }
        __syncthreads();
#pragma unroll
        for (int j = 0; j < 4; j++) *(int4*)(adst + j * 8) = av[j];
#pragma unroll
        for (int j = 0; j < 4; j++) *(s16x8*)(bdst + j * 8) = bp[j];
        __syncthreads();
#pragma unroll
        for (int ks = 0; ks < 2; ks++) {
            const int ko = ks * 32 + (lane >> 4) * 8;
            s16x8 af[4], bfr[4];
#pragma unroll
            for (int f = 0; f < 4; f++)
                af[f] = *(const s16x8*)&As[(wm * 64 + f * 16 + (lane & 15)) * LDK + ko];
#pragma unroll
            for (int f = 0; f < 4; f++)
                bfr[f] = *(const s16x8*)&Bs[(wn * 64 + f * 16 + (lane & 15)) * LDK + ko];
#pragma unroll
            for (int fm = 0; fm < 4; fm++)
#pragma unroll
                for (int fn = 0; fn < 4; fn++)
                    acc[fm][fn] = __builtin_amdgcn_mfma_f32_16x16x32_bf16(
                        af[fm], bfr[fn], acc[fm][fn], 0, 0, 0);
        }
    }

#pragma unroll
    for (int fm = 0; fm < 4; fm++) {
        const int mrow = wm * 64 + fm * 16 + ((lane >> 4) << 2);
#pragma unroll
        for (int fn = 0; fn < 4; fn++) {
            const int ncol = n0 + wn * 64 + fn * 16 + (lane & 15);
#pragma unroll
            for (int r = 0; r < 4; r++) {
                const int m = mrow + r;
                if (m < rows)
                    Y[(size_t)(slotbase + m) * DM + ncol] = acc[fm][fn][r];
            }
        }
    }
}

// ---------------- launch ----------------

extern "C" void kernel_launch(void* const* d_in, const int* in_sizes, int n_in,
                              void* d_out, int out_size, void* d_ws, size_t ws_size,
                              hipStream_t stream) {
    const float* x   = (const float*)d_in[0];
    const float* gw  = (const float*)d_in[1];
    const float* gb  = (const float*)d_in[2];
    const float* w1  = (const float*)d_in[3];
    const float* b1  = (const float*)d_in[4];
    const float* w2  = (const float*)d_in[5];
    const float* b2  = (const float*)d_in[6];
    float* out = (float*)d_out;

    size_t off = 0;
    auto alloc = [&](size_t bytes) {
        void* p = (char*)d_ws + off;
        off += (bytes + 255) & ~(size_t)255;
        return p;
    };
    float* gwT       = (float*)alloc(NE * DM * sizeof(float));
    int*   idx       = (int*)alloc(T2 * sizeof(int));
    float* prob      = (float*)alloc(T2 * sizeof(float));
    int*   counts    = (int*)alloc(32 * sizeof(int));
    int*   offsets   = (int*)alloc(32 * sizeof(int));
    int*   cursors   = (int*)alloc(32 * sizeof(int));
    int*   slot_tok  = (int*)alloc(T2 * sizeof(int));
    int*   pair_slot = (int*)alloc(T2 * sizeof(int));
    unsigned short* Xg = (unsigned short*)alloc((size_t)(T2 + BM) * DM * sizeof(unsigned short));
    unsigned short* Hb = (unsigned short*)alloc((size_t)(T2 + BM) * DF * sizeof(unsigned short));
    float* Yb        = (float*)alloc((size_t)(T2 + BM) * DM * sizeof(float));
    size_t base_need = off;
    unsigned short* W1T = (unsigned short*)alloc((size_t)NE * DM * DF * sizeof(unsigned short));
    unsigned short* W2T = (unsigned short*)alloc((size_t)NE * DF * DM * sizeof(unsigned short));
    const bool big = ws_size >= off;   // ~523 MB needed for the bf16-weight path
    (void)base_need;

    k_transpose_gw<<<NE, 256, 0, stream>>>(gw, gwT);
    k_gate<<<T_TOK / 4, 256, 0, stream>>>(x, gwT, gb, idx, prob);
    k_zero<<<1, 64, 0, stream>>>(counts, cursors);
    k_count<<<T2 / 256, 256, 0, stream>>>(idx, counts);
    k_scan<<<1, 64, 0, stream>>>(counts, offsets);
    k_scatter<<<T2 / 256, 256, 0, stream>>>(idx, offsets, cursors, slot_tok, pair_slot);
    k_gather<<<T2, 256, 0, stream>>>(x, slot_tok, Xg);

    if (big) {
        // pre-pass: W1 [DM][DF] -> W1T [DF][DM]; W2 [DF][DM] -> W2T [DM][DF]
        dim3 gc1(DF / 64, DM / 64, NE);
        k_convT<<<gc1, 256, 0, stream>>>(w1, W1T, DM, DF);
        dim3 gc2(DM / 64, DF / 64, NE);
        k_convT<<<gc2, 256, 0, stream>>>(w2, W2T, DF, DM);

        dim3 g1(DF / BN, NE * MTILES);
        k_mm1<<<g1, 256, 0, stream>>>(Xg, W1T, b1, counts, offsets, Hb);
        dim3 g2(DM / BN, NE * MTILES);
        k_mm2<<<g2, 256, 0, stream>>>(Hb, W2T, counts, offsets, Yb);
    } else {
        dim3 g1(DF / BN, NE * MTILES);
        k_ffn1_o<<<g1, 256, 0, stream>>>(Xg, w1, b1, counts, offsets, Hb);
        dim3 g2(DM / BN, NE * MTILES);
        k_ffn2_o<<<g2, 256, 0, stream>>>(Hb, w2, counts, offsets, Yb);
    }
    k_combine<<<T_TOK, 256, 0, stream>>>(Yb, pair_slot, prob, idx, b2, out);
}